// Round 3
// baseline (180.244 us; speedup 1.0000x reference)
//
#include <hip/hip_runtime.h>
#include <hip/hip_bf16.h>
#include <math.h>

#define NN 512
typedef __attribute__((ext_vector_type(8))) short short8;
typedef __attribute__((ext_vector_type(4))) float f32x4;

// ws float offsets
#define OFF_XL   0u
#define OFF_XR   524288u
#define OFF_VV   1048576u
#define OFF_XLTH 1056768u   // bf16 hi, transposed [inst][64 d][512 j] (262144 floats)
#define OFF_XLTL 1318912u   // bf16 lo
#define OFF_H1   1581056u
#define OFF_H2   2105344u
#define OFF_SA   2629632u

// ---------------- GEMM + v/sa precompute + transposed bf16 hi/lo copies ----------------
template<int K>
__global__ __launch_bounds__(256) void kpre(
    const float* __restrict__ src, int srcPerInst,
    const float* __restrict__ Wl0, const float* __restrict__ Wr0, const float* __restrict__ a0,
    const float* __restrict__ Wl1, const float* __restrict__ Wr1, const float* __restrict__ a1,
    float* __restrict__ ws)
{
    __shared__ float xs[16 * K];
    __shared__ float wbuf[2][32 * 64];
    const int rb   = blockIdx.x;   // 0..31 : 16-row block
    const int inst = blockIdx.y;   // 0..15 (br*8 + batch)
    const int br   = inst >> 3;
    const int tid  = threadIdx.x;
    const int d = tid & 63, ig = tid >> 6;
    const float* Wl = br ? Wl1 : Wl0;
    const float* Wr = br ? Wr1 : Wr0;
    const float* av = br ? a1  : a0;
    const float* sp = src + (size_t)(srcPerInst ? inst : (inst & 7)) * NN * K + (size_t)rb * 16 * K;

    {   // stage 16 rows x K floats (contiguous)
        const float4* s4 = (const float4*)sp;
        float4* d4 = (float4*)xs;
        const int tot = 16 * K / 4;
        for (int i = tid; i < tot; i += 256) d4[i] = s4[i];
    }

    float accl[4] = {0.f,0.f,0.f,0.f}, accr[4] = {0.f,0.f,0.f,0.f};
    const int NC = K / 32;
    for (int kc = 0; kc < NC; ++kc) {
        __syncthreads();
        {   // stage W chunk: 32 k x 64 d x 2 matrices = 16 KB
            const float4* wl4 = (const float4*)(Wl + kc * 32 * 64);
            const float4* wr4 = (const float4*)(Wr + kc * 32 * 64);
            float4* b0 = (float4*)wbuf[0];
            float4* b1 = (float4*)wbuf[1];
            b0[tid] = wl4[tid]; b0[tid + 256] = wl4[tid + 256];
            b1[tid] = wr4[tid]; b1[tid + 256] = wr4[tid + 256];
        }
        __syncthreads();
#pragma unroll
        for (int k4 = 0; k4 < 8; ++k4) {
            float xc[4][4];
#pragma unroll
            for (int rr = 0; rr < 4; ++rr) {
                float4 xv = ((const float4*)xs)[(ig * 4 + rr) * (K / 4) + kc * 8 + k4];
                xc[rr][0] = xv.x; xc[rr][1] = xv.y; xc[rr][2] = xv.z; xc[rr][3] = xv.w;
            }
#pragma unroll
            for (int ee = 0; ee < 4; ++ee) {
                float wl = wbuf[0][(k4 * 4 + ee) * 64 + d];
                float wr = wbuf[1][(k4 * 4 + ee) * 64 + d];
#pragma unroll
                for (int rr = 0; rr < 4; ++rr) {
                    accl[rr] = fmaf(xc[rr][ee], wl, accl[rr]);
                    accr[rr] = fmaf(xc[rr][ee], wr, accr[rr]);
                }
            }
        }
    }

    float aval = av[d];
    float* XL = ws + OFF_XL; float* XR = ws + OFF_XR;
    float* VV = ws + OFF_VV; float* SA = ws + OFF_SA;
    __hip_bfloat16* XLTH = (__hip_bfloat16*)(ws + OFF_XLTH);
    __hip_bfloat16* XLTL = (__hip_bfloat16*)(ws + OFF_XLTL);
#pragma unroll
    for (int rr = 0; rr < 4; ++rr) {
        int row = rb * 16 + ig * 4 + rr;
        size_t o = (size_t)(inst * NN + row) * 64 + d;
        XL[o] = accl[rr];
        XR[o] = accr[rr];
        // transposed bf16 hi/lo copies for the MFMA B-operand
        __hip_bfloat16 h = __float2bfloat16(accl[rr]);
        __hip_bfloat16 lo = __float2bfloat16(accl[rr] - __bfloat162float(h));
        size_t ot = (size_t)(inst * 64 + d) * NN + row;
        XLTH[ot] = h; XLTL[ot] = lo;
        float pv = aval * accl[rr];
#pragma unroll
        for (int mm = 32; mm > 0; mm >>= 1) pv += __shfl_xor(pv, mm, 64);
        if (d == 0) VV[inst * NN + row] = 0.6f * pv;
    }
    if (rb == 0 && ig == 0 && (inst & 7) == 0) SA[br * 64 + d] = 0.4f * aval;
}

// ------- fused attention: VALU scoring + no-max softmax + MFMA PV -------
__global__ __launch_bounds__(256) void kattn(
    const float* __restrict__ ws,
    const float* __restrict__ b0, const float* __restrict__ b1,
    float* __restrict__ Hout)
{
    __shared__ float xt[2][4096];           // xl tile f32, dbuf, linear (gl_lds dest)
    __shared__ __hip_bfloat16 phb[1024];    // p hi frags [16 i][8 swizzled 16B chunks]
    __shared__ __hip_bfloat16 plb[1024];    // p lo frags
    __shared__ float lsum_s[16];

    const int ib   = blockIdx.x;            // 0..31 : 16 i-rows
    const int inst = blockIdx.y;            // 0..15
    const int br   = inst >> 3;
    const int tid  = threadIdx.x;
    const int lane = tid & 63;
    const int wu   = __builtin_amdgcn_readfirstlane(tid >> 6);   // wave id (uniform)
    const float* XL = ws + OFF_XL + (size_t)inst * NN * 64;
    const float* XR = ws + OFF_XR + (size_t)inst * NN * 64;
    const float* VV = ws + OFF_VV + inst * NN;
    const float* SA = ws + OFF_SA + br * 64;
    const __hip_bfloat16* XLTH = (const __hip_bfloat16*)(ws + OFF_XLTH) + (size_t)inst * 64 * NN;
    const __hip_bfloat16* XLTL = (const __hip_bfloat16*)(ws + OFF_XLTL) + (size_t)inst * 64 * NN;
    const float* bias = br ? b1 : b0;
    const int r0 = ib * 16 + wu * 4;

    // prologue: stage tiles 0,1 via global_load_lds (pre-swizzled source, linear dest)
#pragma unroll
    for (int tt = 0; tt < 2; ++tt)
#pragma unroll
        for (int c = 0; c < 4; ++c) {
            int s = c * 256 + wu * 64 + lane;
            int j = s >> 4, ch = (s & 15) ^ (j & 15);
            const float* gsrc = XL + (size_t)tt * 4096 + j * 64 + ch * 4;
            __builtin_amdgcn_global_load_lds(
                (const __attribute__((address_space(1))) void*)gsrc,
                (__attribute__((address_space(3))) void*)&xt[tt][(c * 256 + wu * 64) * 4],
                16, 0, 0);
        }
    __syncthreads();

    f32x4 acc = {0.f, 0.f, 0.f, 0.f};
    float psum[4] = {0.f, 0.f, 0.f, 0.f};

    for (int t = 0; t < 8; ++t) {
        const int buf = t & 1;
        // B-operand loads for PV (global, L2-hot, used after barrier 2)
        float4 bh4[2], bl4[2];
#pragma unroll
        for (int ks = 0; ks < 2; ++ks) {
            size_t bidx = (size_t)(wu * 16 + (lane & 15)) * NN + t * 64 + ks * 32 + (lane >> 4) * 8;
            bh4[ks] = *(const float4*)&XLTH[bidx];
            bl4[ks] = *(const float4*)&XLTL[bidx];
        }
        float vj = VV[t * 64 + lane];

        // per-lane xl row (swizzled read -> conflict-free b128)
        float4 xlv4[16];
#pragma unroll
        for (int q = 0; q < 16; ++q)
            xlv4[q] = ((const float4*)xt[buf])[lane * 16 + (q ^ (lane & 15))];
        __syncthreads();   // b1: all waves done reading buf

        if (t < 6) {       // restage buf with tile t+2 (async; drained by next syncthreads)
#pragma unroll
            for (int c = 0; c < 4; ++c) {
                int s = c * 256 + wu * 64 + lane;
                int j = s >> 4, ch = (s & 15) ^ (j & 15);
                const float* gsrc = XL + (size_t)(t + 2) * 4096 + j * 64 + ch * 4;
                __builtin_amdgcn_global_load_lds(
                    (const __attribute__((address_space(1))) void*)gsrc,
                    (__attribute__((address_space(3))) void*)&xt[buf][(c * 256 + wu * 64) * 4],
                    16, 0, 0);
            }
        }

        // ---- scoring: e' = v_j + sum_d sa_d * |xr_id + xl_jd|  (u_i cancels in softmax) ----
        float c0[4], c1[4], c2[4], c3[4];
#pragma unroll
        for (int ii = 0; ii < 4; ++ii) { c0[ii]=0.f; c1[ii]=0.f; c2[ii]=0.f; c3[ii]=0.f; }
#pragma unroll
        for (int q = 0; q < 16; ++q) {
            float4 x4 = xlv4[q];
            float4 s4 = ((const float4*)SA)[q];                       // uniform -> s_load
#pragma unroll
            for (int ii = 0; ii < 4; ++ii) {
                float4 r4 = ((const float4*)(XR + (size_t)(r0 + ii) * 64))[q];  // uniform -> s_load
                c0[ii] = fmaf(s4.x, fabsf(r4.x + x4.x), c0[ii]);
                c1[ii] = fmaf(s4.y, fabsf(r4.y + x4.y), c1[ii]);
                c2[ii] = fmaf(s4.z, fabsf(r4.z + x4.z), c2[ii]);
                c3[ii] = fmaf(s4.w, fabsf(r4.w + x4.w), c3[ii]);
            }
        }

        // ---- p = exp(e'), hi/lo bf16 split, write A-frags (swizzled chunks) ----
#pragma unroll
        for (int ii = 0; ii < 4; ++ii) {
            float e = vj + ((c0[ii] + c1[ii]) + (c2[ii] + c3[ii]));
            float p = __expf(e);
            psum[ii] += p;
            __hip_bfloat16 h  = __float2bfloat16(p);
            __hip_bfloat16 lo = __float2bfloat16(p - __bfloat162float(h));
            int r = wu * 4 + ii;
            int jc = lane >> 3;
            int idx = r * 64 + (((jc) ^ (r & 7)) << 3) + (lane & 7);
            phb[idx] = h; plb[idx] = lo;
        }
        __syncthreads();   // b2: p-frags visible

        // ---- PV via MFMA: wave wu computes out[0..15][wu*16..+15] ----
#pragma unroll
        for (int ks = 0; ks < 2; ++ks) {
            int aidx = (lane & 15) * 64 + ((((ks << 2) + (lane >> 4)) ^ (lane & 7)) << 3);
            short8 ah = *(const short8*)&phb[aidx];
            short8 al = *(const short8*)&plb[aidx];
            short8 bh = __builtin_bit_cast(short8, bh4[ks]);
            short8 bl = __builtin_bit_cast(short8, bl4[ks]);
            acc = __builtin_amdgcn_mfma_f32_16x16x32_bf16(ah, bh, acc, 0, 0, 0);
            acc = __builtin_amdgcn_mfma_f32_16x16x32_bf16(al, bh, acc, 0, 0, 0);
            acc = __builtin_amdgcn_mfma_f32_16x16x32_bf16(ah, bl, acc, 0, 0, 0);
        }
    }

    // ---- row sums (one tree per row), then epilogue ----
#pragma unroll
    for (int ii = 0; ii < 4; ++ii) {
        float s = psum[ii];
#pragma unroll
        for (int mm = 32; mm > 0; mm >>= 1) s += __shfl_xor(s, mm, 64);
        if (lane == 0) lsum_s[wu * 4 + ii] = s;
    }
    __syncthreads();

    float bv = bias[wu * 16 + (lane & 15)];
#pragma unroll
    for (int r = 0; r < 4; ++r) {
        int row = (lane >> 4) * 4 + r;
        float v = acc[r] / lsum_s[row] + bv;
        float th = 1.f - 2.f / (__expf(2.f * v) + 1.f);   // tanh
        Hout[(size_t)(inst * NN + ib * 16 + row) * 64 + wu * 16 + (lane & 15)] = th;
    }
}

// ---------------- mean-pool over nodes ----------------
__global__ __launch_bounds__(1024) void kpool(const float* __restrict__ H2, float* __restrict__ out)
{
    __shared__ float red[16][64];
    const int inst = blockIdx.x;
    const int tid = threadIdx.x, ig = tid >> 6, lane = tid & 63;
    float s = 0.f;
    for (int i = ig; i < NN; i += 16) s += H2[(size_t)(inst * NN + i) * 64 + lane];
    red[ig][lane] = s;
    __syncthreads();
    if (tid < 64) {
        float v = 0.f;
#pragma unroll
        for (int k = 0; k < 16; ++k) v += red[k][tid];
        out[inst * 64 + tid] = v * (1.f / NN);
    }
}

extern "C" void kernel_launch(void* const* d_in, const int* in_sizes, int n_in,
                              void* d_out, int out_size, void* d_ws, size_t ws_size,
                              hipStream_t stream)
{
    (void)in_sizes; (void)n_in; (void)out_size; (void)ws_size;
    const float* feat  = (const float*)d_in[0];
    const float* p1_Wl = (const float*)d_in[1],  *p1_Wr = (const float*)d_in[2];
    const float* p1_a  = (const float*)d_in[3],  *p1_b  = (const float*)d_in[4];
    const float* p2_Wl = (const float*)d_in[5],  *p2_Wr = (const float*)d_in[6];
    const float* p2_a  = (const float*)d_in[7],  *p2_b  = (const float*)d_in[8];
    const float* v1_Wl = (const float*)d_in[9],  *v1_Wr = (const float*)d_in[10];
    const float* v1_a  = (const float*)d_in[11], *v1_b  = (const float*)d_in[12];
    const float* v2_Wl = (const float*)d_in[13], *v2_Wr = (const float*)d_in[14];
    const float* v2_a  = (const float*)d_in[15], *v2_b  = (const float*)d_in[16];

    float* ws = (float*)d_ws;
    float* H1 = ws + OFF_H1;
    float* H2 = ws + OFF_H2;
    float* out = (float*)d_out;

    // layer 1 (input: features, K=128)
    kpre<128><<<dim3(32, 16), 256, 0, stream>>>(feat, 0, p1_Wl, p1_Wr, p1_a,
                                                v1_Wl, v1_Wr, v1_a, ws);
    kattn<<<dim3(32, 16), 256, 0, stream>>>(ws, p1_b, v1_b, H1);
    // layer 2 (input: H1, K=64)
    kpre<64><<<dim3(32, 16), 256, 0, stream>>>(H1, 1, p2_Wl, p2_Wr, p2_a,
                                               v2_Wl, v2_Wr, v2_a, ws);
    kattn<<<dim3(32, 16), 256, 0, stream>>>(ws, p2_b, v2_b, H2);
    // pool
    kpool<<<16, 1024, 0, stream>>>(H2, out);
}

// Round 4
// 94.818 us; speedup vs baseline: 1.9010x; 1.9010x over previous
//
#include <hip/hip_runtime.h>
#include <hip/hip_bf16.h>
#include <math.h>

#define NN 512
typedef __attribute__((ext_vector_type(8))) short short8;
typedef __attribute__((ext_vector_type(4))) float f32x4;

// ws float offsets
#define OFF_XLI  0u         // interleaved xl: [inst][t=j>>6][q=d>>2][j&63][d&3]
#define OFF_XR   524288u
#define OFF_VV   1048576u
#define OFF_SA   1056768u
#define OFF_XLTH 1056896u   // bf16 hi, transposed [inst][d][j]
#define OFF_XLTL 1319040u   // bf16 lo
#define OFF_H1   1581184u
#define OFF_H2   2105472u

// ---------------- GEMM + v/sa + interleaved & transposed copies ----------------
template<int K>
__global__ __launch_bounds__(256) void kpre(
    const float* __restrict__ src, int srcPerInst,
    const float* __restrict__ Wl0, const float* __restrict__ Wr0, const float* __restrict__ a0,
    const float* __restrict__ Wl1, const float* __restrict__ Wr1, const float* __restrict__ a1,
    float* __restrict__ ws)
{
    __shared__ float xs[8 * K];
    const int rb   = blockIdx.x;   // 0..63 : 8-row block
    const int inst = blockIdx.y;   // 0..15 (br*8 + batch)
    const int br   = inst >> 3;
    const int tid  = threadIdx.x;
    const int d = tid & 63, ig = tid >> 6;
    const float* Wl = br ? Wl1 : Wl0;
    const float* Wr = br ? Wr1 : Wr0;
    const float* av = br ? a1  : a0;
    const float* sp = src + (size_t)(srcPerInst ? inst : (inst & 7)) * NN * K + (size_t)rb * 8 * K;

    if (tid < 2 * K) ((float4*)xs)[tid] = ((const float4*)sp)[tid];
    __syncthreads();

    float accl[2] = {0.f, 0.f}, accr[2] = {0.f, 0.f};
#pragma unroll 8
    for (int k = 0; k < K; ++k) {
        float wl = Wl[k * 64 + d];            // coalesced, L2-hot
        float wr = Wr[k * 64 + d];
#pragma unroll
        for (int rr = 0; rr < 2; ++rr) {
            float xv = xs[(ig * 2 + rr) * K + k];   // wave-uniform broadcast
            accl[rr] = fmaf(xv, wl, accl[rr]);
            accr[rr] = fmaf(xv, wr, accr[rr]);
        }
    }

    float aval = av[d];
    float* XLI = ws + OFF_XLI; float* XR = ws + OFF_XR;
    float* VV  = ws + OFF_VV;  float* SA = ws + OFF_SA;
    __hip_bfloat16* XLTH = (__hip_bfloat16*)(ws + OFF_XLTH);
    __hip_bfloat16* XLTL = (__hip_bfloat16*)(ws + OFF_XLTL);
#pragma unroll
    for (int rr = 0; rr < 2; ++rr) {
        int row = rb * 8 + ig * 2 + rr;
        XR[(size_t)(inst * NN + row) * 64 + d] = accr[rr];
        // interleaved xl for kattn's coalesced per-lane row loads
        XLI[(((size_t)inst * 8 + (row >> 6)) * 16 + (d >> 2)) * 256 + (row & 63) * 4 + (d & 3)] = accl[rr];
        // transposed bf16 hi/lo for the MFMA B-operand
        __hip_bfloat16 h  = __float2bfloat16(accl[rr]);
        __hip_bfloat16 lo = __float2bfloat16(accl[rr] - __bfloat162float(h));
        size_t ot = (size_t)(inst * 64 + d) * NN + row;
        XLTH[ot] = h; XLTL[ot] = lo;
        float pv = aval * accl[rr];
#pragma unroll
        for (int mm = 32; mm > 0; mm >>= 1) pv += __shfl_xor(pv, mm, 64);
        if (d == 0) VV[inst * NN + row] = 0.6f * pv;
    }
    if (rb == 0 && ig == 0 && (inst & 7) == 0) SA[br * 64 + d] = 0.4f * aval;
}

// ------- fused attention: 8 waves x 64 j each, no tile loop, MFMA PV + den -------
__global__ __launch_bounds__(512, 4) void kattn(
    const float* __restrict__ ws,
    const float* __restrict__ b0, const float* __restrict__ b1,
    float* __restrict__ Hout)
{
    __shared__ float xr_s[16 * 64];     // block's 16 xr rows (4 KB)
    __shared__ float sa_s[64];
    __shared__ float redbuf[8448];      // union: phb/plb (32 KB) then pout[8][16][66]

    const int ib   = blockIdx.x;        // 0..31 : 16 i-rows
    const int inst = blockIdx.y;        // 0..15
    const int br   = inst >> 3;
    const int tid  = threadIdx.x;
    const int lane = tid & 63;
    const int w    = __builtin_amdgcn_readfirstlane(tid >> 6);   // wave id 0..7
    const float* XR = ws + OFF_XR + (size_t)inst * NN * 64;
    const float* VV = ws + OFF_VV + inst * NN;
    const __hip_bfloat16* XLTH = (const __hip_bfloat16*)(ws + OFF_XLTH) + (size_t)inst * 64 * NN;
    const __hip_bfloat16* XLTL = (const __hip_bfloat16*)(ws + OFF_XLTL) + (size_t)inst * 64 * NN;
    const float* bias = br ? b1 : b0;

    // per-lane xl row (j = w*64+lane), coalesced from interleaved layout; loaded once
    const float4* xli4 = (const float4*)(ws + OFF_XLI) + ((size_t)inst * 8 + w) * 1024;
    float4 xlv[16];
#pragma unroll
    for (int q = 0; q < 16; ++q) xlv[q] = xli4[q * 64 + lane];
    float vj = VV[w * 64 + lane];

    if (tid < 256) ((float4*)xr_s)[tid] = ((const float4*)(XR + (size_t)ib * 16 * 64))[tid];
    if (tid < 16)  ((float4*)sa_s)[tid] = ((const float4*)(ws + OFF_SA + br * 64))[tid];
    __syncthreads();   // b1: xr/sa staged

    // ---------------- scoring: e[i] for this lane's j ----------------
    float e[16];
#pragma unroll
    for (int ii = 0; ii < 16; ++ii) e[ii] = 0.f;
#pragma unroll
    for (int q = 0; q < 16; ++q) {
        float4 x4 = xlv[q];
        float4 s4 = ((const float4*)sa_s)[q];                 // broadcast
#pragma unroll
        for (int ii = 0; ii < 16; ++ii) {
            float4 r4 = ((const float4*)xr_s)[ii * 16 + q];   // broadcast
            e[ii] = fmaf(s4.x, fabsf(r4.x + x4.x), e[ii]);
            e[ii] = fmaf(s4.y, fabsf(r4.y + x4.y), e[ii]);
            e[ii] = fmaf(s4.z, fabsf(r4.z + x4.z), e[ii]);
            e[ii] = fmaf(s4.w, fabsf(r4.w + x4.w), e[ii]);
        }
    }

    // ---------------- p = exp, bf16 hi/lo, wave-private transpose in LDS ----------------
    __hip_bfloat16* phw = (__hip_bfloat16*)redbuf + w * 2048;        // 1024 hi
    __hip_bfloat16* plw = phw + 1024;                                // 1024 lo
#pragma unroll
    for (int ii = 0; ii < 16; ++ii) {
        float p = __expf(e[ii] + vj);
        __hip_bfloat16 h  = __float2bfloat16(p);
        __hip_bfloat16 lo = __float2bfloat16(p - __bfloat162float(h));
        int idx = ii * 64 + ((((lane >> 3)) ^ (ii & 7)) << 3) + (lane & 7);
        phw[idx] = h; plw[idx] = lo;
    }

    // ---------------- PV + den via MFMA (wave-private A-frags: no barrier) ----------------
    f32x4 accn[4] = {{0,0,0,0},{0,0,0,0},{0,0,0,0},{0,0,0,0}};
    f32x4 accd = {0, 0, 0, 0};
    const short8 ones = {16256,16256,16256,16256,16256,16256,16256,16256};  // bf16 1.0
#pragma unroll
    for (int ks = 0; ks < 2; ++ks) {
        int aidx = (lane & 15) * 64 + ((((ks << 2) + (lane >> 4)) ^ (lane & 7)) << 3);
        short8 ah = *(const short8*)&phw[aidx];
        short8 al = *(const short8*)&plw[aidx];
        int jb = w * 64 + ks * 32 + (lane >> 4) * 8;
#pragma unroll
        for (int dt = 0; dt < 4; ++dt) {
            float4 bhv = *(const float4*)&XLTH[(size_t)(dt * 16 + (lane & 15)) * NN + jb];
            float4 blv = *(const float4*)&XLTL[(size_t)(dt * 16 + (lane & 15)) * NN + jb];
            short8 bh = __builtin_bit_cast(short8, bhv);
            short8 bl = __builtin_bit_cast(short8, blv);
            accn[dt] = __builtin_amdgcn_mfma_f32_16x16x32_bf16(ah, bh, accn[dt], 0, 0, 0);
            accn[dt] = __builtin_amdgcn_mfma_f32_16x16x32_bf16(al, bh, accn[dt], 0, 0, 0);
            accn[dt] = __builtin_amdgcn_mfma_f32_16x16x32_bf16(ah, bl, accn[dt], 0, 0, 0);
        }
        accd = __builtin_amdgcn_mfma_f32_16x16x32_bf16(ah, ones, accd, 0, 0, 0);
        accd = __builtin_amdgcn_mfma_f32_16x16x32_bf16(al, ones, accd, 0, 0, 0);
    }
    __syncthreads();   // b2: everyone done reading phb/plb (pout overwrites that region)

    // partial outs -> LDS: pout[w][i][66] (d 0..63, den at 64)
    float* pw = redbuf + w * 1056;
#pragma unroll
    for (int dt = 0; dt < 4; ++dt)
#pragma unroll
        for (int r = 0; r < 4; ++r)
            pw[((lane >> 4) * 4 + r) * 66 + dt * 16 + (lane & 15)] = accn[dt][r];
    if ((lane & 15) == 0) {
#pragma unroll
        for (int r = 0; r < 4; ++r)
            pw[((lane >> 4) * 4 + r) * 66 + 64] = accd[r];
    }
    __syncthreads();   // b3: partials visible

    // ---------------- cross-wave reduction + epilogue ----------------
    {
        int i  = tid >> 5;         // 0..15
        int dd = tid & 31;         // d pair
        float s0 = 0.f, s1 = 0.f, dn = 0.f;
#pragma unroll
        for (int ww = 0; ww < 8; ++ww) {
            const float* pb = redbuf + ww * 1056 + i * 66;
            float2 v = *(const float2*)&pb[dd * 2];
            s0 += v.x; s1 += v.y; dn += pb[64];
        }
        float inv = 1.f / dn;
        float v0 = s0 * inv + bias[dd * 2];
        float v1 = s1 * inv + bias[dd * 2 + 1];
        float t0 = 1.f - 2.f / (__expf(2.f * v0) + 1.f);
        float t1 = 1.f - 2.f / (__expf(2.f * v1) + 1.f);
        float2 o = make_float2(t0, t1);
        *(float2*)&Hout[(size_t)(inst * NN + ib * 16 + i) * 64 + dd * 2] = o;
    }
}

// ---------------- mean-pool over nodes ----------------
__global__ __launch_bounds__(1024) void kpool(const float* __restrict__ H2, float* __restrict__ out)
{
    __shared__ float red[16][64];
    const int inst = blockIdx.x;
    const int tid = threadIdx.x, ig = tid >> 6, lane = tid & 63;
    float s = 0.f;
    for (int i = ig; i < NN; i += 16) s += H2[(size_t)(inst * NN + i) * 64 + lane];
    red[ig][lane] = s;
    __syncthreads();
    if (tid < 64) {
        float v = 0.f;
#pragma unroll
        for (int k = 0; k < 16; ++k) v += red[k][tid];
        out[inst * 64 + tid] = v * (1.f / NN);
    }
}

extern "C" void kernel_launch(void* const* d_in, const int* in_sizes, int n_in,
                              void* d_out, int out_size, void* d_ws, size_t ws_size,
                              hipStream_t stream)
{
    (void)in_sizes; (void)n_in; (void)out_size; (void)ws_size;
    const float* feat  = (const float*)d_in[0];
    const float* p1_Wl = (const float*)d_in[1],  *p1_Wr = (const float*)d_in[2];
    const float* p1_a  = (const float*)d_in[3],  *p1_b  = (const float*)d_in[4];
    const float* p2_Wl = (const float*)d_in[5],  *p2_Wr = (const float*)d_in[6];
    const float* p2_a  = (const float*)d_in[7],  *p2_b  = (const float*)d_in[8];
    const float* v1_Wl = (const float*)d_in[9],  *v1_Wr = (const float*)d_in[10];
    const float* v1_a  = (const float*)d_in[11], *v1_b  = (const float*)d_in[12];
    const float* v2_Wl = (const float*)d_in[13], *v2_Wr = (const float*)d_in[14];
    const float* v2_a  = (const float*)d_in[15], *v2_b  = (const float*)d_in[16];

    float* ws = (float*)d_ws;
    float* H1 = ws + OFF_H1;
    float* H2 = ws + OFF_H2;
    float* out = (float*)d_out;

    // layer 1 (input: features, K=128)
    kpre<128><<<dim3(64, 16), 256, 0, stream>>>(feat, 0, p1_Wl, p1_Wr, p1_a,
                                                v1_Wl, v1_Wr, v1_a, ws);
    kattn<<<dim3(32, 16), 512, 0, stream>>>(ws, p1_b, v1_b, H1);
    // layer 2 (input: H1, K=64)
    kpre<64><<<dim3(64, 16), 256, 0, stream>>>(H1, 1, p2_Wl, p2_Wr, p2_a,
                                               v2_Wl, v2_Wr, v2_a, ws);
    kattn<<<dim3(32, 16), 512, 0, stream>>>(ws, p2_b, v2_b, H2);
    // pool
    kpool<<<16, 1024, 0, stream>>>(H2, out);
}